// Round 1
// baseline (348.732 us; speedup 1.0000x reference)
//
#include <hip/hip_runtime.h>
#include <cstdint>

typedef __attribute__((ext_vector_type(8))) short bfrag_t;   // 8 x bf16 (4 VGPR)
typedef __attribute__((ext_vector_type(4))) float f32x4_t;   // MFMA acc

#define MFMA16(a,b,c) __builtin_amdgcn_mfma_f32_16x16x32_bf16((a),(b),(c),0,0,0)

__device__ __forceinline__ unsigned short f2bf(float f){
  unsigned u = __float_as_uint(f);
  unsigned r = u + 0x7fffu + ((u >> 16) & 1u);   // round-to-nearest-even
  return (unsigned short)(r >> 16);
}

// ---------------- f32 -> bf16 convert (vectorized) ----------------
__global__ __launch_bounds__(256) void k_cvt(const float* __restrict__ in,
                                             unsigned short* __restrict__ out, int n4){
  int i = blockIdx.x*blockDim.x + threadIdx.x;
  int stride = gridDim.x*blockDim.x;
  for(; i < n4; i += stride){
    float4 v = ((const float4*)in)[i];
    ushort4 o;
    o.x = f2bf(v.x); o.y = f2bf(v.y); o.z = f2bf(v.z); o.w = f2bf(v.w);
    ((ushort4*)out)[i] = o;
  }
}

// ---------------- f32 [R][C] -> bf16 [C][R] transpose ----------------
__global__ __launch_bounds__(256) void k_transpose(const float* __restrict__ in,
                                                   unsigned short* __restrict__ out,
                                                   int R, int C){
  __shared__ unsigned short tile[32][33];
  int bc = blockIdx.x*32, br = blockIdx.y*32;
  int tx = threadIdx.x & 31, ty = threadIdx.x >> 5;  // ty 0..7
  #pragma unroll
  for(int i=0;i<32;i+=8){
    tile[ty+i][tx] = f2bf(in[(size_t)(br+ty+i)*C + bc + tx]);
  }
  __syncthreads();
  #pragma unroll
  for(int i=0;i<32;i+=8){
    out[(size_t)(bc+ty+i)*R + br + tx] = tile[tx][ty+i];
  }
}

// ---------------- bf16 GEMM: C[M][N] = A[M][K] * Bt[N][K]^T ----------------
// 128x128 tile, 4 waves (2x2), BK=32, 16x16x32 MFMA, reg-staged LDS with XOR swizzle.
// EPI 0: scatter to Q (scaled), K, V^T.  EPI 1: f32 out + bias.
template<int EPI>
__global__ __launch_bounds__(256) void k_gemm(
    const unsigned short* __restrict__ A,
    const unsigned short* __restrict__ Bt,
    int M, int N, int K,
    unsigned short* __restrict__ Qo, unsigned short* __restrict__ Ko,
    unsigned short* __restrict__ Vt,
    float* __restrict__ Co, const float* __restrict__ bias)
{
  __shared__ unsigned short lds[2*128*32];
  unsigned short* ldsA = lds;
  unsigned short* ldsB = lds + 128*32;

  const int tid = threadIdx.x;
  const int lane = tid & 63;
  const int w = tid >> 6;
  const int wr = w >> 1, wc = w & 1;
  const int col16 = lane & 15, g = lane >> 4;

  const int bm = blockIdx.y * 128;
  const int bn = blockIdx.x * 128;

  // staging: 512 16B-units per tile; thread handles q0=tid, q1=tid+256
  const int q0 = tid, q1 = tid + 256;
  const int r0 = q0>>2, s0 = q0&3, g0 = s0 ^ ((r0>>1)&3);
  const int r1 = q1>>2, s1 = q1&3, g1 = s1 ^ ((r1>>1)&3);

  const unsigned short* pA0 = A  + (size_t)(bm + r0)*K + g0*8;
  const unsigned short* pA1 = A  + (size_t)(bm + r1)*K + g1*8;
  const unsigned short* pB0 = Bt + (size_t)(bn + r0)*K + g0*8;
  const unsigned short* pB1 = Bt + (size_t)(bn + r1)*K + g1*8;

  f32x4_t acc[4][4];
  #pragma unroll
  for(int i=0;i<4;i++)
    #pragma unroll
    for(int j=0;j<4;j++) acc[i][j] = (f32x4_t)0.0f;

  for(int k0=0; k0<K; k0+=32){
    bfrag_t a0 = *(const bfrag_t*)(pA0 + k0);
    bfrag_t a1 = *(const bfrag_t*)(pA1 + k0);
    bfrag_t b0 = *(const bfrag_t*)(pB0 + k0);
    bfrag_t b1 = *(const bfrag_t*)(pB1 + k0);
    __syncthreads();   // all waves done reading previous tile
    *(bfrag_t*)(ldsA + q0*8) = a0;
    *(bfrag_t*)(ldsA + q1*8) = a1;
    *(bfrag_t*)(ldsB + q0*8) = b0;
    *(bfrag_t*)(ldsB + q1*8) = b1;
    __syncthreads();
    bfrag_t af[4], bfr[4];
    #pragma unroll
    for(int mi=0;mi<4;mi++){
      int row = wr*64 + mi*16 + col16;
      int slot = g ^ ((row>>1)&3);
      af[mi] = *(const bfrag_t*)(ldsA + row*32 + slot*8);
    }
    #pragma unroll
    for(int ni=0;ni<4;ni++){
      int row = wc*64 + ni*16 + col16;
      int slot = g ^ ((row>>1)&3);
      bfr[ni] = *(const bfrag_t*)(ldsB + row*32 + slot*8);
    }
    #pragma unroll
    for(int mi=0;mi<4;mi++)
      #pragma unroll
      for(int ni=0;ni<4;ni++)
        acc[mi][ni] = MFMA16(af[mi], bfr[ni], acc[mi][ni]);
  }

  if (EPI == 0){
    #pragma unroll
    for(int mi=0;mi<4;mi++){
      int mrow = bm + wr*64 + mi*16 + g*4;
      #pragma unroll
      for(int ni=0;ni<4;ni++){
        int ncol = bn + wc*64 + ni*16 + col16;
        int which = ncol >> 10, rem = ncol & 1023;
        int h = rem >> 6, d = rem & 63;
        #pragma unroll
        for(int r=0;r<4;r++){
          int m_ = mrow + r;
          int b = m_ >> 11, sq = m_ & 2047;
          size_t bh = (size_t)(b*16 + h);
          float v = acc[mi][ni][r];
          if (which == 0)      Qo[(bh*2048 + sq)*64 + d] = f2bf(v * 0.125f);
          else if (which == 1) Ko[(bh*2048 + sq)*64 + d] = f2bf(v);
          else                 Vt[(bh*64 + d)*2048 + sq] = f2bf(v);
        }
      }
    }
  } else {
    #pragma unroll
    for(int mi=0;mi<4;mi++){
      int mrow = bm + wr*64 + mi*16 + g*4;
      #pragma unroll
      for(int ni=0;ni<4;ni++){
        int ncol = bn + wc*64 + ni*16 + col16;
        float bb = bias[ncol];
        #pragma unroll
        for(int r=0;r<4;r++){
          Co[(size_t)(mrow+r)*N + ncol] = acc[mi][ni][r] + bb;
        }
      }
    }
  }
}

// ---------------- causal flash attention ----------------
// grid (32 qtiles, 32 bh), 256 threads = 4 waves, each wave 16 q rows, KBLK=64.
// Q,K: [bh][2048][64] bf16 (Q pre-scaled).  Vt: [bh][64][2048] bf16.
// O: [b*2048+s][1024] bf16 (head-concat layout).
__global__ __launch_bounds__(256) void k_attn(
    const unsigned short* __restrict__ Q,
    const unsigned short* __restrict__ Kk,
    const unsigned short* __restrict__ Vt,
    unsigned short* __restrict__ O)
{
  __shared__ unsigned short plds[4*16*64];   // per-wave 16x64 P tile, XOR-swizzled
  const int lane = threadIdx.x & 63;
  const int w = threadIdx.x >> 6;
  const int col16 = lane & 15, g = lane >> 4;
  const int qt = blockIdx.x;
  const int bh = blockIdx.y;
  const int b = bh >> 4, h = bh & 15;

  const int qrow0 = qt*64 + w*16;
  const unsigned short* Qb = Q  + (size_t)bh*2048*64;
  const unsigned short* Kb = Kk + (size_t)bh*2048*64;
  const unsigned short* Vb = Vt + (size_t)bh*64*2048;

  bfrag_t qf[2];
  #pragma unroll
  for(int dk=0;dk<2;dk++)
    qf[dk] = *(const bfrag_t*)(Qb + (size_t)(qrow0 + col16)*64 + dk*32 + g*8);

  f32x4_t oacc[4];
  #pragma unroll
  for(int n=0;n<4;n++) oacc[n] = (f32x4_t)0.0f;
  float mrun[4], lrun[4];
  #pragma unroll
  for(int r=0;r<4;r++){ mrun[r] = -1e30f; lrun[r] = 0.f; }

  unsigned short* pw = plds + w*1024;

  const int nkt = qt + 1;
  for(int kt=0; kt<nkt; kt++){
    const int kbase = kt*64;
    // ---- S = Q K^T  (16 q x 64 k) ----
    f32x4_t sacc[4];
    #pragma unroll
    for(int ks=0; ks<4; ks++){
      bfrag_t kf0 = *(const bfrag_t*)(Kb + (size_t)(kbase + ks*16 + col16)*64 +  0 + g*8);
      bfrag_t kf1 = *(const bfrag_t*)(Kb + (size_t)(kbase + ks*16 + col16)*64 + 32 + g*8);
      f32x4_t c = (f32x4_t)0.0f;
      c = MFMA16(qf[0], kf0, c);
      c = MFMA16(qf[1], kf1, c);
      sacc[ks] = c;
    }
    // ---- causal mask (only on the diagonal tile) ----
    if (kt == qt){
      #pragma unroll
      for(int ks=0; ks<4; ks++)
        #pragma unroll
        for(int r=0;r<4;r++){
          int qi = qrow0 + g*4 + r;
          int kj = kbase + ks*16 + col16;
          if (kj > qi) sacc[ks][r] = -1e30f;
        }
    }
    // ---- online softmax ----
    float pm[4];
    #pragma unroll
    for(int r=0;r<4;r++){
      float mx = fmaxf(fmaxf(sacc[0][r], sacc[1][r]), fmaxf(sacc[2][r], sacc[3][r]));
      mx = fmaxf(mx, __shfl_xor(mx, 1));
      mx = fmaxf(mx, __shfl_xor(mx, 2));
      mx = fmaxf(mx, __shfl_xor(mx, 4));
      mx = fmaxf(mx, __shfl_xor(mx, 8));
      pm[r] = mx;
    }
    float alpha[4];
    #pragma unroll
    for(int r=0;r<4;r++){
      float mnew = fmaxf(mrun[r], pm[r]);
      alpha[r] = __expf(mrun[r] - mnew);
      mrun[r] = mnew;
    }
    float rs[4] = {0.f,0.f,0.f,0.f};
    #pragma unroll
    for(int ks=0; ks<4; ks++){
      #pragma unroll
      for(int r=0;r<4;r++){
        float p = __expf(sacc[ks][r] - mrun[r]);
        rs[r] += p;
        int rr = g*4 + r;
        int byteo = ((rr*128) + (ks*16 + col16)*2) ^ ((rr&7)<<4);
        pw[byteo>>1] = f2bf(p);
      }
    }
    #pragma unroll
    for(int r=0;r<4;r++){
      rs[r] += __shfl_xor(rs[r], 1);
      rs[r] += __shfl_xor(rs[r], 2);
      rs[r] += __shfl_xor(rs[r], 4);
      rs[r] += __shfl_xor(rs[r], 8);
      lrun[r] = lrun[r]*alpha[r] + rs[r];
    }
    #pragma unroll
    for(int n=0;n<4;n++)
      #pragma unroll
      for(int r=0;r<4;r++)
        oacc[n][r] *= alpha[r];
    // ---- read back P fragments ----
    bfrag_t pf[2];
    #pragma unroll
    for(int jk=0;jk<2;jk++){
      int byteo = (col16*128 + jk*64 + g*16) ^ ((col16&7)<<4);
      pf[jk] = *(const bfrag_t*)(pw + (byteo>>1));
    }
    // ---- O += P V ----
    #pragma unroll
    for(int n=0;n<4;n++){
      bfrag_t v0 = *(const bfrag_t*)(Vb + (size_t)(n*16 + col16)*2048 + kbase +  0 + g*8);
      bfrag_t v1 = *(const bfrag_t*)(Vb + (size_t)(n*16 + col16)*2048 + kbase + 32 + g*8);
      oacc[n] = MFMA16(pf[0], v0, oacc[n]);
      oacc[n] = MFMA16(pf[1], v1, oacc[n]);
    }
  }
  // ---- epilogue ----
  #pragma unroll
  for(int r=0;r<4;r++){
    float inv = 1.0f / lrun[r];
    int s = qrow0 + g*4 + r;
    size_t obase = ((size_t)(b*2048 + s))*1024 + (size_t)h*64;
    #pragma unroll
    for(int n=0;n<4;n++){
      O[obase + n*16 + col16] = f2bf(oacc[n][r] * inv);
    }
  }
}

// ---------------- launcher ----------------
extern "C" void kernel_launch(void* const* d_in, const int* in_sizes, int n_in,
                              void* d_out, int out_size, void* d_ws, size_t ws_size,
                              hipStream_t stream){
  const float* x     = (const float*)d_in[0];
  const float* w_qkv = (const float*)d_in[1];
  const float* w_out = (const float*)d_in[2];
  const float* b_out = (const float*)d_in[3];
  float* out = (float*)d_out;

  unsigned char* ws = (unsigned char*)d_ws;
  unsigned short* xbf   = (unsigned short*)(ws);                         // 8MB (reused as attn_out)
  unsigned short* wqkvT = (unsigned short*)(ws + (size_t)8*1024*1024);   // 6MB
  unsigned short* woutT = (unsigned short*)(ws + (size_t)14*1024*1024);  // 2MB
  unsigned short* Qb    = (unsigned short*)(ws + (size_t)16*1024*1024);  // 8MB
  unsigned short* Kb    = (unsigned short*)(ws + (size_t)24*1024*1024);  // 8MB
  unsigned short* Vtb   = (unsigned short*)(ws + (size_t)32*1024*1024);  // 8MB
  unsigned short* attno = xbf;  // alias: x_bf16 dead after GEMM1

  k_cvt<<<2048, 256, 0, stream>>>(x, xbf, 4096*1024/4);
  k_transpose<<<dim3(3072/32, 1024/32), 256, 0, stream>>>(w_qkv, wqkvT, 1024, 3072);
  k_transpose<<<dim3(1024/32, 1024/32), 256, 0, stream>>>(w_out, woutT, 1024, 1024);
  k_gemm<0><<<dim3(24, 32), 256, 0, stream>>>(xbf, wqkvT, 4096, 3072, 1024,
                                              Qb, Kb, Vtb, nullptr, nullptr);
  k_attn<<<dim3(32, 32), 256, 0, stream>>>(Qb, Kb, Vtb, attno);
  k_gemm<1><<<dim3(8, 32), 256, 0, stream>>>(attno, woutT, 4096, 1024, 1024,
                                             nullptr, nullptr, nullptr, out, b_out);
}

// Round 2
// 209.730 us; speedup vs baseline: 1.6628x; 1.6628x over previous
//
#include <hip/hip_runtime.h>
#include <cstdint>

typedef __attribute__((ext_vector_type(8))) short bfrag_t;   // 8 x bf16 (4 VGPR)
typedef __attribute__((ext_vector_type(4))) float f32x4_t;   // MFMA acc

#define MFMA16(a,b,c) __builtin_amdgcn_mfma_f32_16x16x32_bf16((a),(b),(c),0,0,0)

__device__ __forceinline__ unsigned short f2bf(float f){
  unsigned u = __float_as_uint(f);
  unsigned r = u + 0x7fffu + ((u >> 16) & 1u);   // round-to-nearest-even
  return (unsigned short)(r >> 16);
}

// ---------------- f32 -> bf16 convert (vectorized) ----------------
__global__ __launch_bounds__(256) void k_cvt(const float* __restrict__ in,
                                             unsigned short* __restrict__ out, int n4){
  int i = blockIdx.x*blockDim.x + threadIdx.x;
  int stride = gridDim.x*blockDim.x;
  for(; i < n4; i += stride){
    float4 v = ((const float4*)in)[i];
    ushort4 o;
    o.x = f2bf(v.x); o.y = f2bf(v.y); o.z = f2bf(v.z); o.w = f2bf(v.w);
    ((ushort4*)out)[i] = o;
  }
}

// ---------------- f32 [R][C] -> bf16 [C][R] transpose ----------------
__global__ __launch_bounds__(256) void k_transpose(const float* __restrict__ in,
                                                   unsigned short* __restrict__ out,
                                                   int R, int C){
  __shared__ unsigned short tile[32][33];
  int bc = blockIdx.x*32, br = blockIdx.y*32;
  int tx = threadIdx.x & 31, ty = threadIdx.x >> 5;  // ty 0..7
  #pragma unroll
  for(int i=0;i<32;i+=8){
    tile[ty+i][tx] = f2bf(in[(size_t)(br+ty+i)*C + bc + tx]);
  }
  __syncthreads();
  #pragma unroll
  for(int i=0;i<32;i+=8){
    out[(size_t)(bc+ty+i)*R + br + tx] = tile[tx][ty+i];
  }
}

// ---------------- bf16 GEMM: C[M][N] = A[M][K] * Bt[N][K]^T ----------------
// 128x128 tile, 4 waves (2x2), BK=32, 16x16x32 MFMA, reg-staged LDS with XOR swizzle.
// EPI 0: scatter to Q (scaled), K, V^T.  EPI 1: f32 out + bias.
template<int EPI>
__global__ __launch_bounds__(256) void k_gemm(
    const unsigned short* __restrict__ A,
    const unsigned short* __restrict__ Bt,
    int M, int N, int K,
    unsigned short* __restrict__ Qo, unsigned short* __restrict__ Ko,
    unsigned short* __restrict__ Vt,
    float* __restrict__ Co, const float* __restrict__ bias)
{
  __shared__ unsigned short lds[2*128*32];
  unsigned short* ldsA = lds;
  unsigned short* ldsB = lds + 128*32;

  const int tid = threadIdx.x;
  const int lane = tid & 63;
  const int w = tid >> 6;
  const int wr = w >> 1, wc = w & 1;
  const int col16 = lane & 15, g = lane >> 4;

  const int bm = blockIdx.y * 128;
  const int bn = blockIdx.x * 128;

  // staging: 512 16B-units per tile; thread handles q0=tid, q1=tid+256
  const int q0 = tid, q1 = tid + 256;
  const int r0 = q0>>2, s0 = q0&3, g0 = s0 ^ ((r0>>1)&3);
  const int r1 = q1>>2, s1 = q1&3, g1 = s1 ^ ((r1>>1)&3);

  const unsigned short* pA0 = A  + (size_t)(bm + r0)*K + g0*8;
  const unsigned short* pA1 = A  + (size_t)(bm + r1)*K + g1*8;
  const unsigned short* pB0 = Bt + (size_t)(bn + r0)*K + g0*8;
  const unsigned short* pB1 = Bt + (size_t)(bn + r1)*K + g1*8;

  f32x4_t acc[4][4];
  #pragma unroll
  for(int i=0;i<4;i++)
    #pragma unroll
    for(int j=0;j<4;j++) acc[i][j] = (f32x4_t)0.0f;

  for(int k0=0; k0<K; k0+=32){
    bfrag_t a0 = *(const bfrag_t*)(pA0 + k0);
    bfrag_t a1 = *(const bfrag_t*)(pA1 + k0);
    bfrag_t b0 = *(const bfrag_t*)(pB0 + k0);
    bfrag_t b1 = *(const bfrag_t*)(pB1 + k0);
    __syncthreads();   // all waves done reading previous tile
    *(bfrag_t*)(ldsA + q0*8) = a0;
    *(bfrag_t*)(ldsA + q1*8) = a1;
    *(bfrag_t*)(ldsB + q0*8) = b0;
    *(bfrag_t*)(ldsB + q1*8) = b1;
    __syncthreads();
    bfrag_t af[4], bfr[4];
    #pragma unroll
    for(int mi=0;mi<4;mi++){
      int row = wr*64 + mi*16 + col16;
      int slot = g ^ ((row>>1)&3);
      af[mi] = *(const bfrag_t*)(ldsA + row*32 + slot*8);
    }
    #pragma unroll
    for(int ni=0;ni<4;ni++){
      int row = wc*64 + ni*16 + col16;
      int slot = g ^ ((row>>1)&3);
      bfr[ni] = *(const bfrag_t*)(ldsB + row*32 + slot*8);
    }
    #pragma unroll
    for(int mi=0;mi<4;mi++)
      #pragma unroll
      for(int ni=0;ni<4;ni++)
        acc[mi][ni] = MFMA16(af[mi], bfr[ni], acc[mi][ni]);
  }

  if (EPI == 0){
    #pragma unroll
    for(int mi=0;mi<4;mi++){
      int mrow = bm + wr*64 + mi*16 + g*4;
      #pragma unroll
      for(int ni=0;ni<4;ni++){
        int ncol = bn + wc*64 + ni*16 + col16;
        int which = ncol >> 10, rem = ncol & 1023;
        int h = rem >> 6, d = rem & 63;
        #pragma unroll
        for(int r=0;r<4;r++){
          int m_ = mrow + r;
          int b = m_ >> 11, sq = m_ & 2047;
          size_t bh = (size_t)(b*16 + h);
          float v = acc[mi][ni][r];
          if (which == 0)      Qo[(bh*2048 + sq)*64 + d] = f2bf(v * 0.125f);
          else if (which == 1) Ko[(bh*2048 + sq)*64 + d] = f2bf(v);
          else                 Vt[(bh*64 + d)*2048 + sq] = f2bf(v);
        }
      }
    }
  } else {
    #pragma unroll
    for(int mi=0;mi<4;mi++){
      int mrow = bm + wr*64 + mi*16 + g*4;
      #pragma unroll
      for(int ni=0;ni<4;ni++){
        int ncol = bn + wc*64 + ni*16 + col16;
        float bb = bias[ncol];
        #pragma unroll
        for(int r=0;r<4;r++){
          Co[(size_t)(mrow+r)*N + ncol] = acc[mi][ni][r] + bb;
        }
      }
    }
  }
}

// ---------------- causal flash attention (v2: paired q-tiles + K prefetch) ----
// grid (16 pairs, 32 bh), 256 threads = 4 waves, each wave 16 q rows, KBLK=64.
// Block p processes q-tiles {p, 31-p}: exactly 33 K-iterations per block.
// Q,K: [bh][2048][64] bf16 (Q pre-scaled).  Vt: [bh][64][2048] bf16.
// O: [b*2048+s][1024] bf16 (head-concat layout).
__global__ __launch_bounds__(256) void k_attn(
    const unsigned short* __restrict__ Q,
    const unsigned short* __restrict__ Kk,
    const unsigned short* __restrict__ Vt,
    unsigned short* __restrict__ O)
{
  __shared__ unsigned short plds[4*16*64];   // per-wave 16x64 P tile, XOR-swizzled
  const int lane = threadIdx.x & 63;
  const int w = threadIdx.x >> 6;
  const int col16 = lane & 15, g = lane >> 4;
  const int p = blockIdx.x;
  const int bh = blockIdx.y;
  const int b = bh >> 4, h = bh & 15;

  const unsigned short* Qb = Q  + (size_t)bh*2048*64;
  const unsigned short* Kb = Kk + (size_t)bh*2048*64;
  const unsigned short* Vb = Vt + (size_t)bh*64*2048;
  unsigned short* pw = plds + w*1024;

  #pragma unroll 1
  for(int sel=0; sel<2; sel++){
    const int qt = sel ? (31 - p) : p;
    const int qrow0 = qt*64 + w*16;
    const int nkt = qt + 1;

    bfrag_t qf[2];
    #pragma unroll
    for(int dk=0;dk<2;dk++)
      qf[dk] = *(const bfrag_t*)(Qb + (size_t)(qrow0 + col16)*64 + dk*32 + g*8);

    f32x4_t oacc[4];
    #pragma unroll
    for(int n=0;n<4;n++) oacc[n] = (f32x4_t)0.0f;
    float mrun[4], lrun[4];
    #pragma unroll
    for(int r=0;r<4;r++){ mrun[r] = -1e30f; lrun[r] = 0.f; }

    bfrag_t kA[4][2], kB[4][2];

    // preload K fragments for kt=0
    #pragma unroll
    for(int ks=0; ks<4; ks++)
      #pragma unroll
      for(int dk=0;dk<2;dk++)
        kA[ks][dk] = *(const bfrag_t*)(Kb + (size_t)(ks*16 + col16)*64 + dk*32 + g*8);

    // body: compute iteration kt with kc, prefetch K for kt+1 into kn
    auto body = [&](int kt, bfrag_t (&kc)[4][2], bfrag_t (&kn)[4][2]){
      const int kbase = kt*64;
      // ---- issue V loads for this tile (used ~end of iteration) ----
      bfrag_t vf[4][2];
      #pragma unroll
      for(int n=0;n<4;n++)
        #pragma unroll
        for(int jk=0;jk<2;jk++)
          vf[n][jk] = *(const bfrag_t*)(Vb + (size_t)(n*16 + col16)*2048 + kbase + jk*32 + g*8);
      // ---- S = Q K^T ----
      f32x4_t sacc[4];
      #pragma unroll
      for(int ks=0; ks<4; ks++){
        f32x4_t c = (f32x4_t)0.0f;
        c = MFMA16(qf[0], kc[ks][0], c);
        c = MFMA16(qf[1], kc[ks][1], c);
        sacc[ks] = c;
      }
      // ---- prefetch K for kt+1 (clamped; harmless if unused) ----
      {
        const int kb2 = (kt+1 < 32 ? kt+1 : 31)*64;
        #pragma unroll
        for(int ks=0; ks<4; ks++)
          #pragma unroll
          for(int dk=0;dk<2;dk++)
            kn[ks][dk] = *(const bfrag_t*)(Kb + (size_t)(kb2 + ks*16 + col16)*64 + dk*32 + g*8);
      }
      // ---- causal mask (diagonal tile only) ----
      if (kt == qt){
        #pragma unroll
        for(int ks=0; ks<4; ks++)
          #pragma unroll
          for(int r=0;r<4;r++){
            int qi = qrow0 + g*4 + r;
            int kj = kbase + ks*16 + col16;
            if (kj > qi) sacc[ks][r] = -1e30f;
          }
      }
      // ---- online softmax ----
      float pm[4];
      #pragma unroll
      for(int r=0;r<4;r++){
        float mx = fmaxf(fmaxf(sacc[0][r], sacc[1][r]), fmaxf(sacc[2][r], sacc[3][r]));
        mx = fmaxf(mx, __shfl_xor(mx, 1));
        mx = fmaxf(mx, __shfl_xor(mx, 2));
        mx = fmaxf(mx, __shfl_xor(mx, 4));
        mx = fmaxf(mx, __shfl_xor(mx, 8));
        pm[r] = mx;
      }
      float alpha[4];
      #pragma unroll
      for(int r=0;r<4;r++){
        float mnew = fmaxf(mrun[r], pm[r]);
        alpha[r] = __expf(mrun[r] - mnew);
        mrun[r] = mnew;
      }
      float rs[4] = {0.f,0.f,0.f,0.f};
      #pragma unroll
      for(int ks=0; ks<4; ks++){
        #pragma unroll
        for(int r=0;r<4;r++){
          float pv = __expf(sacc[ks][r] - mrun[r]);
          rs[r] += pv;
          int rr = g*4 + r;
          int byteo = ((rr*128) + (ks*16 + col16)*2) ^ ((rr&7)<<4);
          pw[byteo>>1] = f2bf(pv);
        }
      }
      #pragma unroll
      for(int r=0;r<4;r++){
        rs[r] += __shfl_xor(rs[r], 1);
        rs[r] += __shfl_xor(rs[r], 2);
        rs[r] += __shfl_xor(rs[r], 4);
        rs[r] += __shfl_xor(rs[r], 8);
        lrun[r] = lrun[r]*alpha[r] + rs[r];
      }
      #pragma unroll
      for(int n=0;n<4;n++)
        #pragma unroll
        for(int r=0;r<4;r++)
          oacc[n][r] *= alpha[r];
      // ---- read back P fragments ----
      bfrag_t pf[2];
      #pragma unroll
      for(int jk=0;jk<2;jk++){
        int byteo = (col16*128 + jk*64 + g*16) ^ ((col16&7)<<4);
        pf[jk] = *(const bfrag_t*)(pw + (byteo>>1));
      }
      // ---- O += P V ----
      #pragma unroll
      for(int n=0;n<4;n++){
        oacc[n] = MFMA16(pf[0], vf[n][0], oacc[n]);
        oacc[n] = MFMA16(pf[1], vf[n][1], oacc[n]);
      }
    };

    int kt = 0;
    #pragma unroll 1
    while (kt < nkt){
      body(kt, kA, kB);
      kt++;
      if (kt >= nkt) break;
      body(kt, kB, kA);
      kt++;
    }

    // ---- epilogue ----
    #pragma unroll
    for(int r=0;r<4;r++){
      float inv = 1.0f / lrun[r];
      int s = qrow0 + g*4 + r;
      size_t obase = ((size_t)(b*2048 + s))*1024 + (size_t)h*64;
      #pragma unroll
      for(int n=0;n<4;n++){
        O[obase + n*16 + col16] = f2bf(oacc[n][r] * inv);
      }
    }
  }
}

// ---------------- launcher ----------------
extern "C" void kernel_launch(void* const* d_in, const int* in_sizes, int n_in,
                              void* d_out, int out_size, void* d_ws, size_t ws_size,
                              hipStream_t stream){
  const float* x     = (const float*)d_in[0];
  const float* w_qkv = (const float*)d_in[1];
  const float* w_out = (const float*)d_in[2];
  const float* b_out = (const float*)d_in[3];
  float* out = (float*)d_out;

  unsigned char* ws = (unsigned char*)d_ws;
  unsigned short* xbf   = (unsigned short*)(ws);                         // 8MB (reused as attn_out)
  unsigned short* wqkvT = (unsigned short*)(ws + (size_t)8*1024*1024);   // 6MB
  unsigned short* woutT = (unsigned short*)(ws + (size_t)14*1024*1024);  // 2MB
  unsigned short* Qb    = (unsigned short*)(ws + (size_t)16*1024*1024);  // 8MB
  unsigned short* Kb    = (unsigned short*)(ws + (size_t)24*1024*1024);  // 8MB
  unsigned short* Vtb   = (unsigned short*)(ws + (size_t)32*1024*1024);  // 8MB
  unsigned short* attno = xbf;  // alias: x_bf16 dead after GEMM1

  k_cvt<<<2048, 256, 0, stream>>>(x, xbf, 4096*1024/4);
  k_transpose<<<dim3(3072/32, 1024/32), 256, 0, stream>>>(w_qkv, wqkvT, 1024, 3072);
  k_transpose<<<dim3(1024/32, 1024/32), 256, 0, stream>>>(w_out, woutT, 1024, 1024);
  k_gemm<0><<<dim3(24, 32), 256, 0, stream>>>(xbf, wqkvT, 4096, 3072, 1024,
                                              Qb, Kb, Vtb, nullptr, nullptr);
  k_attn<<<dim3(16, 32), 256, 0, stream>>>(Qb, Kb, Vtb, attno);
  k_gemm<1><<<dim3(8, 32), 256, 0, stream>>>(attno, woutT, 4096, 1024, 1024,
                                             nullptr, nullptr, nullptr, out, b_out);
}

// Round 3
// 148.333 us; speedup vs baseline: 2.3510x; 1.4139x over previous
//
#include <hip/hip_runtime.h>
#include <cstdint>

typedef __attribute__((ext_vector_type(8))) short bfrag_t;   // 8 x bf16 (4 VGPR)
typedef __attribute__((ext_vector_type(4))) float f32x4_t;   // MFMA acc

#define MFMA16(a,b,c) __builtin_amdgcn_mfma_f32_16x16x32_bf16((a),(b),(c),0,0,0)

__device__ __forceinline__ unsigned short f2bf(float f){
  unsigned u = __float_as_uint(f);
  unsigned r = u + 0x7fffu + ((u >> 16) & 1u);   // round-to-nearest-even
  return (unsigned short)(r >> 16);
}

// async global->LDS, 16B per lane. LDS dest = wave-uniform base + lane*16.
__device__ __forceinline__ void gload16(const unsigned short* g, unsigned short* l){
  __builtin_amdgcn_global_load_lds(
      (const __attribute__((address_space(1))) unsigned int*)(const void*)g,
      (__attribute__((address_space(3))) unsigned int*)(void*)l,
      16, 0, 0);
}

// ---------------- f32 -> bf16 convert (vectorized) ----------------
__global__ __launch_bounds__(256) void k_cvt(const float* __restrict__ in,
                                             unsigned short* __restrict__ out, int n4){
  int i = blockIdx.x*blockDim.x + threadIdx.x;
  int stride = gridDim.x*blockDim.x;
  for(; i < n4; i += stride){
    float4 v = ((const float4*)in)[i];
    ushort4 o;
    o.x = f2bf(v.x); o.y = f2bf(v.y); o.z = f2bf(v.z); o.w = f2bf(v.w);
    ((ushort4*)out)[i] = o;
  }
}

// ---------------- f32 [R][C] -> bf16 [C][R] transpose ----------------
__global__ __launch_bounds__(256) void k_transpose(const float* __restrict__ in,
                                                   unsigned short* __restrict__ out,
                                                   int R, int C){
  __shared__ unsigned short tile[32][33];
  int bc = blockIdx.x*32, br = blockIdx.y*32;
  int tx = threadIdx.x & 31, ty = threadIdx.x >> 5;  // ty 0..7
  #pragma unroll
  for(int i=0;i<32;i+=8){
    tile[ty+i][tx] = f2bf(in[(size_t)(br+ty+i)*C + bc + tx]);
  }
  __syncthreads();
  #pragma unroll
  for(int i=0;i<32;i+=8){
    out[(size_t)(bc+ty+i)*R + br + tx] = tile[tx][ty+i];
  }
}

// ---------------- bf16 GEMM: C[M][N] = A[M][K] * Bt[N][K]^T ----------------
// 128x128 tile, 4 waves (2x2), BK=32, 16x16x32 MFMA, reg-staged LDS with XOR swizzle.
// EPI 0: scatter to Q (scaled, row layout) + K/V fragment-image layout.
// EPI 1: f32 out + bias.
//
// K image per bh (131072 shorts): tile kt (4096 shorts) = [ks*2+dk][lane][8]
//   holding K[bh][kt*64 + ks*16 + (lane&15)][dk*32 + (lane>>4)*8 + e]
// V image per bh: tile kt = [n*2+jk][lane][8]
//   holding V[bh][kt*64 + jk*32 + (lane>>4)*8 + e][n*16 + (lane&15)]
template<int EPI>
__global__ __launch_bounds__(256) void k_gemm(
    const unsigned short* __restrict__ A,
    const unsigned short* __restrict__ Bt,
    int M, int N, int K,
    unsigned short* __restrict__ Qo, unsigned short* __restrict__ Kimg,
    unsigned short* __restrict__ Vimg,
    float* __restrict__ Co, const float* __restrict__ bias)
{
  __shared__ unsigned short lds[2*128*32];
  unsigned short* ldsA = lds;
  unsigned short* ldsB = lds + 128*32;

  const int tid = threadIdx.x;
  const int lane = tid & 63;
  const int w = tid >> 6;
  const int wr = w >> 1, wc = w & 1;
  const int col16 = lane & 15, g = lane >> 4;

  const int bm = blockIdx.y * 128;
  const int bn = blockIdx.x * 128;

  const int q0 = tid, q1 = tid + 256;
  const int r0 = q0>>2, s0 = q0&3, g0 = s0 ^ ((r0>>1)&3);
  const int r1 = q1>>2, s1 = q1&3, g1 = s1 ^ ((r1>>1)&3);

  const unsigned short* pA0 = A  + (size_t)(bm + r0)*K + g0*8;
  const unsigned short* pA1 = A  + (size_t)(bm + r1)*K + g1*8;
  const unsigned short* pB0 = Bt + (size_t)(bn + r0)*K + g0*8;
  const unsigned short* pB1 = Bt + (size_t)(bn + r1)*K + g1*8;

  f32x4_t acc[4][4];
  #pragma unroll
  for(int i=0;i<4;i++)
    #pragma unroll
    for(int j=0;j<4;j++) acc[i][j] = (f32x4_t)0.0f;

  for(int k0=0; k0<K; k0+=32){
    bfrag_t a0 = *(const bfrag_t*)(pA0 + k0);
    bfrag_t a1 = *(const bfrag_t*)(pA1 + k0);
    bfrag_t b0 = *(const bfrag_t*)(pB0 + k0);
    bfrag_t b1 = *(const bfrag_t*)(pB1 + k0);
    __syncthreads();
    *(bfrag_t*)(ldsA + q0*8) = a0;
    *(bfrag_t*)(ldsA + q1*8) = a1;
    *(bfrag_t*)(ldsB + q0*8) = b0;
    *(bfrag_t*)(ldsB + q1*8) = b1;
    __syncthreads();
    bfrag_t af[4], bfr[4];
    #pragma unroll
    for(int mi=0;mi<4;mi++){
      int row = wr*64 + mi*16 + col16;
      int slot = g ^ ((row>>1)&3);
      af[mi] = *(const bfrag_t*)(ldsA + row*32 + slot*8);
    }
    #pragma unroll
    for(int ni=0;ni<4;ni++){
      int row = wc*64 + ni*16 + col16;
      int slot = g ^ ((row>>1)&3);
      bfr[ni] = *(const bfrag_t*)(ldsB + row*32 + slot*8);
    }
    #pragma unroll
    for(int mi=0;mi<4;mi++)
      #pragma unroll
      for(int ni=0;ni<4;ni++)
        acc[mi][ni] = MFMA16(af[mi], bfr[ni], acc[mi][ni]);
  }

  if (EPI == 0){
    #pragma unroll
    for(int mi=0;mi<4;mi++){
      int mrow = bm + wr*64 + mi*16 + g*4;
      #pragma unroll
      for(int ni=0;ni<4;ni++){
        int ncol = bn + wc*64 + ni*16 + col16;
        int which = ncol >> 10, rem = ncol & 1023;
        int h = rem >> 6, d = rem & 63;
        #pragma unroll
        for(int r=0;r<4;r++){
          int m_ = mrow + r;
          int b = m_ >> 11, sq = m_ & 2047;
          size_t bh = (size_t)(b*16 + h);
          float v = acc[mi][ni][r];
          if (which == 0){
            Qo[(bh*2048 + sq)*64 + d] = f2bf(v * 0.125f);
          } else if (which == 1){
            // K fragment image
            int kt = sq >> 6, rr = sq & 63;
            int ks = rr >> 4, c16 = rr & 15;
            int dk = d >> 5, g3 = (d >> 3) & 3, e = d & 7;
            size_t off = bh*131072 + (size_t)kt*4096
                       + (size_t)(ks*2 + dk)*512 + (size_t)(g3*16 + c16)*8 + e;
            Kimg[off] = f2bf(v);
          } else {
            // V fragment image
            int kt = sq >> 6, sc = sq & 63;
            int jk = sc >> 5, g3 = (sc >> 3) & 3, e = sc & 7;
            int n = d >> 4, c16 = d & 15;
            size_t off = bh*131072 + (size_t)kt*4096
                       + (size_t)(n*2 + jk)*512 + (size_t)(g3*16 + c16)*8 + e;
            Vimg[off] = f2bf(v);
          }
        }
      }
    }
  } else {
    #pragma unroll
    for(int mi=0;mi<4;mi++){
      int mrow = bm + wr*64 + mi*16 + g*4;
      #pragma unroll
      for(int ni=0;ni<4;ni++){
        int ncol = bn + wc*64 + ni*16 + col16;
        float bb = bias[ncol];
        #pragma unroll
        for(int r=0;r<4;r++){
          Co[(size_t)(mrow+r)*N + ncol] = acc[mi][ni][r] + bb;
        }
      }
    }
  }
}

// ---------------- causal flash attention (v3: LDS-staged K/V, XCD-local) ----
// grid (32 bh, 16 pairs), 256 threads = 4 waves, each wave 16 q rows, KBLK=64.
// Block (bh,p) processes q-tiles {p, 31-p}: exactly 33 K-iterations.
// Q: [bh][2048][64] bf16 (pre-scaled). Kimg/Vimg: fragment-image tiles (see k_gemm).
// O: [b*2048+s][1024] bf16.
__global__ __launch_bounds__(256) void k_attn(
    const unsigned short* __restrict__ Q,
    const unsigned short* __restrict__ Kimg,
    const unsigned short* __restrict__ Vimg,
    unsigned short* __restrict__ O)
{
  __shared__ unsigned short kls[2*4096];     // K tiles, double-buffered (8KB each)
  __shared__ unsigned short vls[2*4096];     // V tiles
  __shared__ unsigned short plds[4*16*64];   // per-wave 16x64 P tile, XOR-swizzled
  const int lane = threadIdx.x & 63;
  const int w = threadIdx.x >> 6;
  const int col16 = lane & 15, g = lane >> 4;
  const int bh = blockIdx.x;
  const int p = blockIdx.y;
  const int b = bh >> 4, h = bh & 15;

  const unsigned short* Qb = Q    + (size_t)bh*2048*64;
  const unsigned short* Kb = Kimg + (size_t)bh*131072;
  const unsigned short* Vb = Vimg + (size_t)bh*131072;
  unsigned short* pw = plds + w*1024;

  // stage tile kt of K and V into buffer bsel; each wave moves 2KB of each
  auto stage = [&](int kt, int bsel){
    const unsigned short* gk = Kb + (size_t)kt*4096;
    const unsigned short* gv = Vb + (size_t)kt*4096;
    unsigned short* lk = kls + bsel*4096;
    unsigned short* lv = vls + bsel*4096;
    #pragma unroll
    for(int c=0;c<2;c++){
      int chunk = w*2 + c;               // 0..7, 1KB each
      int u = chunk*64 + lane;           // 16B-unit index
      gload16(gk + u*8, lk + chunk*512);
      gload16(gv + u*8, lv + chunk*512);
    }
  };

  #pragma unroll 1
  for(int sel=0; sel<2; sel++){
    const int qt = sel ? (31 - p) : p;
    const int qrow0 = qt*64 + w*16;
    const int nkt = qt + 1;

    bfrag_t qf[2];
    #pragma unroll
    for(int dk=0;dk<2;dk++)
      qf[dk] = *(const bfrag_t*)(Qb + (size_t)(qrow0 + col16)*64 + dk*32 + g*8);

    f32x4_t oacc[4];
    #pragma unroll
    for(int n=0;n<4;n++) oacc[n] = (f32x4_t)0.0f;
    float mrun[4], lrun[4];
    #pragma unroll
    for(int r=0;r<4;r++){ mrun[r] = -1e30f; lrun[r] = 0.f; }

    stage(0, 0);
    __syncthreads();

    #pragma unroll 1
    for(int kt=0; kt<nkt; kt++){
      const int cur = kt & 1;
      if (kt+1 < nkt) stage(kt+1, cur^1);

      const bfrag_t* kb = (const bfrag_t*)(kls + cur*4096);
      const bfrag_t* vb = (const bfrag_t*)(vls + cur*4096);

      // ---- S = Q K^T ----
      bfrag_t kf[4][2];
      #pragma unroll
      for(int ks=0; ks<4; ks++)
        #pragma unroll
        for(int dk=0;dk<2;dk++)
          kf[ks][dk] = kb[(ks*2+dk)*64 + lane];
      f32x4_t sacc[4];
      #pragma unroll
      for(int ks=0; ks<4; ks++){
        f32x4_t c = (f32x4_t)0.0f;
        c = MFMA16(qf[0], kf[ks][0], c);
        c = MFMA16(qf[1], kf[ks][1], c);
        sacc[ks] = c;
      }
      // ---- causal mask (diagonal tile only) ----
      if (kt == qt){
        const int kbase = kt*64;
        #pragma unroll
        for(int ks=0; ks<4; ks++)
          #pragma unroll
          for(int r=0;r<4;r++){
            int qi = qrow0 + g*4 + r;
            int kj = kbase + ks*16 + col16;
            if (kj > qi) sacc[ks][r] = -1e30f;
          }
      }
      // ---- online softmax ----
      float pm[4];
      #pragma unroll
      for(int r=0;r<4;r++){
        float mx = fmaxf(fmaxf(sacc[0][r], sacc[1][r]), fmaxf(sacc[2][r], sacc[3][r]));
        mx = fmaxf(mx, __shfl_xor(mx, 1));
        mx = fmaxf(mx, __shfl_xor(mx, 2));
        mx = fmaxf(mx, __shfl_xor(mx, 4));
        mx = fmaxf(mx, __shfl_xor(mx, 8));
        pm[r] = mx;
      }
      float alpha[4];
      #pragma unroll
      for(int r=0;r<4;r++){
        float mnew = fmaxf(mrun[r], pm[r]);
        alpha[r] = __expf(mrun[r] - mnew);
        mrun[r] = mnew;
      }
      float rs[4] = {0.f,0.f,0.f,0.f};
      #pragma unroll
      for(int ks=0; ks<4; ks++){
        #pragma unroll
        for(int r=0;r<4;r++){
          float pv = __expf(sacc[ks][r] - mrun[r]);
          rs[r] += pv;
          int rr = g*4 + r;
          int byteo = ((rr*128) + (ks*16 + col16)*2) ^ ((rr&7)<<4);
          pw[byteo>>1] = f2bf(pv);
        }
      }
      #pragma unroll
      for(int r=0;r<4;r++){
        rs[r] += __shfl_xor(rs[r], 1);
        rs[r] += __shfl_xor(rs[r], 2);
        rs[r] += __shfl_xor(rs[r], 4);
        rs[r] += __shfl_xor(rs[r], 8);
        lrun[r] = lrun[r]*alpha[r] + rs[r];
      }
      #pragma unroll
      for(int n=0;n<4;n++)
        #pragma unroll
        for(int r=0;r<4;r++)
          oacc[n][r] *= alpha[r];
      // ---- read back P fragments ----
      bfrag_t pf[2];
      #pragma unroll
      for(int jk=0;jk<2;jk++){
        int byteo = (col16*128 + jk*64 + g*16) ^ ((col16&7)<<4);
        pf[jk] = *(const bfrag_t*)(pw + (byteo>>1));
      }
      // ---- O += P V ----
      bfrag_t vf[4][2];
      #pragma unroll
      for(int n=0;n<4;n++)
        #pragma unroll
        for(int jk=0;jk<2;jk++)
          vf[n][jk] = vb[(n*2+jk)*64 + lane];
      #pragma unroll
      for(int n=0;n<4;n++){
        oacc[n] = MFMA16(pf[0], vf[n][0], oacc[n]);
        oacc[n] = MFMA16(pf[1], vf[n][1], oacc[n]);
      }
      __syncthreads();   // stage(kt+1) landed; all waves done with buf[cur]
    }

    // ---- epilogue ----
    #pragma unroll
    for(int r=0;r<4;r++){
      float inv = 1.0f / lrun[r];
      int s = qrow0 + g*4 + r;
      size_t obase = ((size_t)(b*2048 + s))*1024 + (size_t)h*64;
      #pragma unroll
      for(int n=0;n<4;n++){
        O[obase + n*16 + col16] = f2bf(oacc[n][r] * inv);
      }
    }
  }
}

// ---------------- launcher ----------------
extern "C" void kernel_launch(void* const* d_in, const int* in_sizes, int n_in,
                              void* d_out, int out_size, void* d_ws, size_t ws_size,
                              hipStream_t stream){
  const float* x     = (const float*)d_in[0];
  const float* w_qkv = (const float*)d_in[1];
  const float* w_out = (const float*)d_in[2];
  const float* b_out = (const float*)d_in[3];
  float* out = (float*)d_out;

  unsigned char* ws = (unsigned char*)d_ws;
  unsigned short* xbf   = (unsigned short*)(ws);                         // 8MB (reused as attn_out)
  unsigned short* wqkvT = (unsigned short*)(ws + (size_t)8*1024*1024);   // 6MB
  unsigned short* woutT = (unsigned short*)(ws + (size_t)14*1024*1024);  // 2MB
  unsigned short* Qb    = (unsigned short*)(ws + (size_t)16*1024*1024);  // 8MB
  unsigned short* Kb    = (unsigned short*)(ws + (size_t)24*1024*1024);  // 8MB
  unsigned short* Vtb   = (unsigned short*)(ws + (size_t)32*1024*1024);  // 8MB
  unsigned short* attno = xbf;  // alias: x_bf16 dead after GEMM1

  k_cvt<<<2048, 256, 0, stream>>>(x, xbf, 4096*1024/4);
  k_transpose<<<dim3(3072/32, 1024/32), 256, 0, stream>>>(w_qkv, wqkvT, 1024, 3072);
  k_transpose<<<dim3(1024/32, 1024/32), 256, 0, stream>>>(w_out, woutT, 1024, 1024);
  k_gemm<0><<<dim3(24, 32), 256, 0, stream>>>(xbf, wqkvT, 4096, 3072, 1024,
                                              Qb, Kb, Vtb, nullptr, nullptr);
  k_attn<<<dim3(32, 16), 256, 0, stream>>>(Qb, Kb, Vtb, attno);
  k_gemm<1><<<dim3(8, 32), 256, 0, stream>>>(attno, woutT, 4096, 1024, 1024,
                                             nullptr, nullptr, nullptr, out, b_out);
}

// Round 4
// 122.681 us; speedup vs baseline: 2.8426x; 1.2091x over previous
//
#include <hip/hip_runtime.h>
#include <cstdint>

typedef __attribute__((ext_vector_type(8))) short bfrag_t;   // 8 x bf16 (4 VGPR)
typedef __attribute__((ext_vector_type(4))) float f32x4_t;   // MFMA acc

#define MFMA16(a,b,c) __builtin_amdgcn_mfma_f32_16x16x32_bf16((a),(b),(c),0,0,0)

__device__ __forceinline__ unsigned short f2bf(float f){
  unsigned u = __float_as_uint(f);
  unsigned r = u + 0x7fffu + ((u >> 16) & 1u);   // round-to-nearest-even
  return (unsigned short)(r >> 16);
}

// pack 2 f32 -> 2 bf16 in one u32 (lo = a, hi = b)
__device__ __forceinline__ unsigned pk2bf(float a, float b){
  unsigned r;
  asm("v_cvt_pk_bf16_f32 %0, %1, %2" : "=v"(r) : "v"(a), "v"(b));
  return r;
}

// async global->LDS, 16B per lane. LDS dest = wave-uniform base + lane*16.
__device__ __forceinline__ void gload16(const unsigned short* g, unsigned short* l){
  __builtin_amdgcn_global_load_lds(
      (const __attribute__((address_space(1))) unsigned int*)(const void*)g,
      (__attribute__((address_space(3))) unsigned int*)(void*)l,
      16, 0, 0);
}

// ---------------- f32 -> bf16 convert (vectorized) ----------------
__global__ __launch_bounds__(256) void k_cvt(const float* __restrict__ in,
                                             unsigned short* __restrict__ out, int n4){
  int i = blockIdx.x*blockDim.x + threadIdx.x;
  int stride = gridDim.x*blockDim.x;
  for(; i < n4; i += stride){
    float4 v = ((const float4*)in)[i];
    ushort4 o;
    o.x = f2bf(v.x); o.y = f2bf(v.y); o.z = f2bf(v.z); o.w = f2bf(v.w);
    ((ushort4*)out)[i] = o;
  }
}

// ---------------- f32 [R][C] -> bf16 [C][R] transpose ----------------
__global__ __launch_bounds__(256) void k_transpose(const float* __restrict__ in,
                                                   unsigned short* __restrict__ out,
                                                   int R, int C){
  __shared__ unsigned short tile[32][33];
  int bc = blockIdx.x*32, br = blockIdx.y*32;
  int tx = threadIdx.x & 31, ty = threadIdx.x >> 5;  // ty 0..7
  #pragma unroll
  for(int i=0;i<32;i+=8){
    tile[ty+i][tx] = f2bf(in[(size_t)(br+ty+i)*C + bc + tx]);
  }
  __syncthreads();
  #pragma unroll
  for(int i=0;i<32;i+=8){
    out[(size_t)(bc+ty+i)*R + br + tx] = tile[tx][ty+i];
  }
}

// ---------------- bf16 GEMM: C[M][N] = A[M][K] * Bt[N][K]^T ----------------
// BM x 128 tile, 4 waves, BK=32, 16x16x32 MFMA.
// Staging via global_load_lds (16B), XOR slot swizzle applied on SOURCE address
// (LDS dest linear), read back with matching XOR -> 2-way (free) bank aliasing.
// EPI 0 (BM=128): scatter to Q (scaled) + K/V fragment-image layout.
// EPI 1 (BM=64):  f32 out + bias.
template<int EPI, int BM>
__global__ __launch_bounds__(256) void k_gemm(
    const unsigned short* __restrict__ A,
    const unsigned short* __restrict__ Bt,
    int M, int N, int K,
    unsigned short* __restrict__ Qo, unsigned short* __restrict__ Kimg,
    unsigned short* __restrict__ Vimg,
    float* __restrict__ Co, const float* __restrict__ bias)
{
  constexpr int WM = (BM==128) ? 2 : 1;   // waves in M
  constexpr int WN = 4/WM;                // waves in N
  constexpr int MI = BM/(16*WM);          // 16-row tiles per wave in M
  constexpr int NI = 128/(16*WN);         // per wave in N

  __shared__ unsigned short ldsA[BM*32];
  __shared__ unsigned short ldsB[128*32];

  const int tid = threadIdx.x;
  const int lane = tid & 63;
  const int w = tid >> 6;
  const int wr = w / WN, wc = w % WN;
  const int col16 = lane & 15, g = lane >> 4;

  const int bm = blockIdx.y * BM;
  const int bn = blockIdx.x * 128;

  f32x4_t acc[MI][NI];
  #pragma unroll
  for(int i=0;i<MI;i++)
    #pragma unroll
    for(int j=0;j<NI;j++) acc[i][j] = (f32x4_t)0.0f;

  for(int k0=0; k0<K; k0+=32){
    __syncthreads();   // all waves done reading previous tile
    // stage A (BM*4 16B-units) and B (512 units)
    #pragma unroll
    for(int i=0; i<BM*4/256; i++){
      int u = i*256 + tid;
      int row = u>>2, s = u&3, gs = s ^ ((row>>1)&3);
      gload16(A + (size_t)(bm+row)*K + k0 + gs*8, ldsA + (i*256 + w*64)*8);
    }
    #pragma unroll
    for(int i=0; i<2; i++){
      int u = i*256 + tid;
      int row = u>>2, s = u&3, gs = s ^ ((row>>1)&3);
      gload16(Bt + (size_t)(bn+row)*K + k0 + gs*8, ldsB + (i*256 + w*64)*8);
    }
    __syncthreads();   // compiler emits vmcnt(0) before barrier -> loads landed
    bfrag_t af[MI], bfr[NI];
    #pragma unroll
    for(int mi=0;mi<MI;mi++){
      int row = wr*(MI*16) + mi*16 + col16;
      int slot = g ^ ((row>>1)&3);
      af[mi] = *(const bfrag_t*)(ldsA + row*32 + slot*8);
    }
    #pragma unroll
    for(int ni=0;ni<NI;ni++){
      int row = wc*(NI*16) + ni*16 + col16;
      int slot = g ^ ((row>>1)&3);
      bfr[ni] = *(const bfrag_t*)(ldsB + row*32 + slot*8);
    }
    #pragma unroll
    for(int mi=0;mi<MI;mi++)
      #pragma unroll
      for(int ni=0;ni<NI;ni++)
        acc[mi][ni] = MFMA16(af[mi], bfr[ni], acc[mi][ni]);
  }

  if (EPI == 0){
    #pragma unroll
    for(int mi=0;mi<MI;mi++){
      int mrow = bm + wr*(MI*16) + mi*16 + g*4;
      #pragma unroll
      for(int ni=0;ni<NI;ni++){
        int ncol = bn + wc*(NI*16) + ni*16 + col16;
        int which = ncol >> 10, rem = ncol & 1023;
        int h = rem >> 6, d = rem & 63;
        #pragma unroll
        for(int r=0;r<4;r++){
          int m_ = mrow + r;
          int b = m_ >> 11, sq = m_ & 2047;
          size_t bh = (size_t)(b*16 + h);
          float v = acc[mi][ni][r];
          if (which == 0){
            Qo[(bh*2048 + sq)*64 + d] = f2bf(v * 0.125f);
          } else if (which == 1){
            // K fragment image: tile kt = [ks*2+dk][lane][8]
            int kt = sq >> 6, rr = sq & 63;
            int ks = rr >> 4, c16 = rr & 15;
            int dk = d >> 5, g3 = (d >> 3) & 3, e = d & 7;
            size_t off = bh*131072 + (size_t)kt*4096
                       + (size_t)(ks*2 + dk)*512 + (size_t)(g3*16 + c16)*8 + e;
            Kimg[off] = f2bf(v);
          } else {
            // V fragment image: tile kt = [n*2+jk][lane][8]
            int kt = sq >> 6, sc = sq & 63;
            int jk = sc >> 5, g3 = (sc >> 3) & 3, e = sc & 7;
            int n = d >> 4, c16 = d & 15;
            size_t off = bh*131072 + (size_t)kt*4096
                       + (size_t)(n*2 + jk)*512 + (size_t)(g3*16 + c16)*8 + e;
            Vimg[off] = f2bf(v);
          }
        }
      }
    }
  } else {
    #pragma unroll
    for(int mi=0;mi<MI;mi++){
      int mrow = bm + wr*(MI*16) + mi*16 + g*4;
      #pragma unroll
      for(int ni=0;ni<NI;ni++){
        int ncol = bn + wc*(NI*16) + ni*16 + col16;
        float bb = bias[ncol];
        #pragma unroll
        for(int r=0;r<4;r++){
          Co[(size_t)(mrow+r)*N + ncol] = acc[mi][ni][r] + bb;
        }
      }
    }
  }
}

// ---------------- causal flash attention (v4: swapped operands, lane-owned rows)
// grid (32 bh, 32 y), qt = 31-y (longest first), 256 threads = 4 waves,
// wave w owns q rows qt*64+w*16 .. +15; lane (g,c) owns q row qt*64+w*16+c.
// QK^T swapped: S^T[k=g*4+r][q=c]; PV swapped: O^T[d=g*4+r][q=c].
// Softmax stats are per-lane scalars; defer-max (THR=8) skips rescale.
__global__ __launch_bounds__(256, 4) void k_attn(
    const unsigned short* __restrict__ Q,
    const unsigned short* __restrict__ Kimg,
    const unsigned short* __restrict__ Vimg,
    unsigned short* __restrict__ O)
{
  __shared__ unsigned short kls[2*4096];     // K tiles, double-buffered (8KB each)
  __shared__ unsigned short vls[2*4096];     // V tiles
  __shared__ unsigned short plds[4*1024];    // per-wave 16x64 P tile, XOR-swizzled
  const int lane = threadIdx.x & 63;
  const int w = threadIdx.x >> 6;
  const int col16 = lane & 15, g = lane >> 4;
  const int bh = blockIdx.x;
  const int qt = 31 - blockIdx.y;
  const int b = bh >> 4, h = bh & 15;

  const unsigned short* Qb = Q    + (size_t)bh*2048*64;
  const unsigned short* Kb = Kimg + (size_t)bh*131072;
  const unsigned short* Vb = Vimg + (size_t)bh*131072;
  char* pw = (char*)(plds + w*1024);

  auto stage = [&](int kt, int bsel){
    const unsigned short* gk = Kb + (size_t)kt*4096;
    const unsigned short* gv = Vb + (size_t)kt*4096;
    unsigned short* lk = kls + bsel*4096;
    unsigned short* lv = vls + bsel*4096;
    #pragma unroll
    for(int c=0;c<2;c++){
      int chunk = w*2 + c;               // 0..7, 1KB each
      int u = chunk*64 + lane;           // 16B-unit index
      gload16(gk + u*8, lk + chunk*512);
      gload16(gv + u*8, lv + chunk*512);
    }
  };

  const int qrow0 = qt*64 + w*16;
  const int nkt = qt + 1;
  const int qi = qrow0 + col16;          // this lane's q row

  bfrag_t qf[2];
  #pragma unroll
  for(int dk=0;dk<2;dk++)
    qf[dk] = *(const bfrag_t*)(Qb + (size_t)(qrow0 + col16)*64 + dk*32 + g*8);

  f32x4_t oaccT[4];
  #pragma unroll
  for(int n=0;n<4;n++) oaccT[n] = (f32x4_t)0.0f;
  float mrun = -1e30f, lrun = 0.f;

  stage(0, 0);
  __syncthreads();

  #pragma unroll 1
  for(int kt=0; kt<nkt; kt++){
    const int cur = kt & 1;
    if (kt+1 < nkt) stage(kt+1, cur^1);

    const bfrag_t* kb = (const bfrag_t*)(kls + cur*4096);
    const bfrag_t* vb = (const bfrag_t*)(vls + cur*4096);

    // ---- S^T = K Q^T : sacc[ks][r] = S[q=qi][k = kt*64 + ks*16 + g*4 + r]
    f32x4_t sacc[4];
    #pragma unroll
    for(int ks=0; ks<4; ks++){
      bfrag_t kf0 = kb[(ks*2+0)*64 + lane];
      bfrag_t kf1 = kb[(ks*2+1)*64 + lane];
      f32x4_t c = (f32x4_t)0.0f;
      c = MFMA16(kf0, qf[0], c);
      c = MFMA16(kf1, qf[1], c);
      sacc[ks] = c;
    }
    // ---- causal mask (diagonal tile only) ----
    if (kt == qt){
      const int kbase = kt*64;
      #pragma unroll
      for(int ks=0; ks<4; ks++)
        #pragma unroll
        for(int r=0;r<4;r++){
          int kj = kbase + ks*16 + g*4 + r;
          if (kj > qi) sacc[ks][r] = -1e30f;
        }
    }
    // ---- per-lane row max (16 in-lane + 2 shfl) ----
    float pm = fmaxf(
        fmaxf(fmaxf(fmaxf(sacc[0][0],sacc[0][1]),fmaxf(sacc[0][2],sacc[0][3])),
              fmaxf(fmaxf(sacc[1][0],sacc[1][1]),fmaxf(sacc[1][2],sacc[1][3]))),
        fmaxf(fmaxf(fmaxf(sacc[2][0],sacc[2][1]),fmaxf(sacc[2][2],sacc[2][3])),
              fmaxf(fmaxf(sacc[3][0],sacc[3][1]),fmaxf(sacc[3][2],sacc[3][3]))));
    pm = fmaxf(pm, __shfl_xor(pm, 16));
    pm = fmaxf(pm, __shfl_xor(pm, 32));
    // ---- defer-max: rescale only if some row's max grew by >8 ----
    if (!__all(pm - mrun <= 8.0f)){
      float mnew = fmaxf(mrun, pm);
      float alpha = __expf(mrun - mnew);
      mrun = mnew;
      lrun *= alpha;
      #pragma unroll
      for(int n=0;n<4;n++)
        #pragma unroll
        for(int r=0;r<4;r++)
          oaccT[n][r] *= alpha;
    }
    // ---- P = exp(S - m), pack to bf16, write swizzled LDS row q=c ----
    float rs = 0.f;
    #pragma unroll
    for(int ks=0; ks<4; ks++){
      float p0 = __expf(sacc[ks][0] - mrun);
      float p1 = __expf(sacc[ks][1] - mrun);
      float p2 = __expf(sacc[ks][2] - mrun);
      float p3 = __expf(sacc[ks][3] - mrun);
      rs += (p0+p1)+(p2+p3);
      unsigned w0 = pk2bf(p0, p1);
      unsigned w1 = pk2bf(p2, p3);
      int byte0 = (col16*128 + (ks*16 + g*4)*2) ^ ((col16&7)<<4);
      *(unsigned*)(pw + byte0)     = w0;
      *(unsigned*)(pw + byte0 + 4) = w1;
    }
    rs += __shfl_xor(rs, 16);
    rs += __shfl_xor(rs, 32);
    lrun += rs;
    // ---- read P as B-fragment: P[q=c][k=jk*32+g*8+e] ----
    bfrag_t pf[2];
    #pragma unroll
    for(int jk=0;jk<2;jk++){
      int byteo = (col16*128 + jk*64 + g*16) ^ ((col16&7)<<4);
      pf[jk] = *(const bfrag_t*)(pw + byteo);
    }
    // ---- O^T += V^T P^T ----
    #pragma unroll
    for(int n=0;n<4;n++){
      bfrag_t v0 = vb[(n*2+0)*64 + lane];
      bfrag_t v1 = vb[(n*2+1)*64 + lane];
      oaccT[n] = MFMA16(v0, pf[0], oaccT[n]);
      oaccT[n] = MFMA16(v1, pf[1], oaccT[n]);
    }
    __syncthreads();   // stage(kt+1) landed; all waves done with buf[cur]
  }

  // ---- epilogue: lane owns q row qi; d = n*16 + g*4 + r ----
  {
    float inv = 1.0f / lrun;
    size_t obase = ((size_t)(b*2048 + qi))*1024 + (size_t)h*64;
    #pragma unroll
    for(int n=0;n<4;n++){
      unsigned w0 = pk2bf(oaccT[n][0]*inv, oaccT[n][1]*inv);
      unsigned w1 = pk2bf(oaccT[n][2]*inv, oaccT[n][3]*inv);
      uint2 pkd; pkd.x = w0; pkd.y = w1;
      *(uint2*)(O + obase + n*16 + g*4) = pkd;
    }
  }
}

// ---------------- launcher ----------------
extern "C" void kernel_launch(void* const* d_in, const int* in_sizes, int n_in,
                              void* d_out, int out_size, void* d_ws, size_t ws_size,
                              hipStream_t stream){
  const float* x     = (const float*)d_in[0];
  const float* w_qkv = (const float*)d_in[1];
  const float* w_out = (const float*)d_in[2];
  const float* b_out = (const float*)d_in[3];
  float* out = (float*)d_out;

  unsigned char* ws = (unsigned char*)d_ws;
  unsigned short* xbf   = (unsigned short*)(ws);                         // 8MB (reused as attn_out)
  unsigned short* wqkvT = (unsigned short*)(ws + (size_t)8*1024*1024);   // 6MB
  unsigned short* woutT = (unsigned short*)(ws + (size_t)14*1024*1024);  // 2MB
  unsigned short* Qb    = (unsigned short*)(ws + (size_t)16*1024*1024);  // 8MB
  unsigned short* Kb    = (unsigned short*)(ws + (size_t)24*1024*1024);  // 8MB
  unsigned short* Vtb   = (unsigned short*)(ws + (size_t)32*1024*1024);  // 8MB
  unsigned short* attno = xbf;  // alias: x_bf16 dead after GEMM1

  k_cvt<<<2048, 256, 0, stream>>>(x, xbf, 4096*1024/4);
  k_transpose<<<dim3(3072/32, 1024/32), 256, 0, stream>>>(w_qkv, wqkvT, 1024, 3072);
  k_transpose<<<dim3(1024/32, 1024/32), 256, 0, stream>>>(w_out, woutT, 1024, 1024);
  k_gemm<0,128><<<dim3(24, 32), 256, 0, stream>>>(xbf, wqkvT, 4096, 3072, 1024,
                                                  Qb, Kb, Vtb, nullptr, nullptr);
  k_attn<<<dim3(32, 32), 256, 0, stream>>>(Qb, Kb, Vtb, attno);
  k_gemm<1,64><<<dim3(8, 64), 256, 0, stream>>>(attno, woutT, 4096, 1024, 1024,
                                                nullptr, nullptr, nullptr, out, b_out);
}